// Round 6
// baseline (3616.801 us; speedup 1.0000x reference)
//
#include <hip/hip_runtime.h>
#include <hip/hip_bf16.h>

// HMM backward recursion, B=32, T=256, H=1024, V=50257.
// y_s[b,i] = N_{s-1}[b] + log( sum_j expA[i,j] * Y_{s-1}[b,j] ) + e_t[b,i]
// Y_s = exp(y_s - N_s), N_s = max_i y_{s-1}[b,i] (one-step-stale upper bound).
//
// 16 persistent worker WGs exchange Y/flags through either:
//   FAST path: sc0 loads/stores (coherent within one XCD's L2) — only if the
//              workers verified they share an L2 (token test), else
//   SAFE path: sc0 sc1 (device-scope, memory/L3 coherence point) — round-4
//              proven behavior.
// Claim protocol guarantees 16 slots fill (last 16 blocks claim
// unconditionally); verification is bounded-spin; mode agreement goes through
// the SAFE channel. No path can deadlock.

#define Hdim 1024
#define Bdim 32
#define Tdim 256
#define Vdim 50257
#define NWG  16
#define SLICE 64
#define NBLK 512
#define VBOUND 1500

typedef __attribute__((ext_vector_type(8))) __bf16 bf16x8;
typedef __attribute__((ext_vector_type(4))) float  f32x4;
typedef __attribute__((ext_vector_type(4))) unsigned u32x4;

// workspace layout (bytes)
#define OFF_ABF   0                          // exp(alpha) bf16: 2 MB
#define OFF_YBUF  2097152                    // [2][16][4096B] = 131072
#define OFF_PSUM  (OFF_YBUF + 131072)        // 32 f32 (pad 128)
#define OFF_RBUF  (OFF_PSUM + 128)           // 32 f32 (pad 128)
#define OFF_LREC  (OFF_RBUF + 128)           // [2][16] records x 256 B = 8192
#define OFF_CTL   (OFF_LREC + 8192)          // [0]=homeXcd, [16]=slotCnt
#define OFF_VER   (OFF_CTL + 128)            // verTok[16] @0, verOk[16] @128
#define OFF_END0  (OFF_VER + 256)
#define OFF_E     (((OFF_END0) + 4095) & ~4095)
#define WS_E_NEED ((size_t)OFF_E + (size_t)Tdim * Bdim * Hdim * 4)

// LDS carve
#define SM_A       131072                    // 64 rows x 1024 bf16 (swizzled)
#define SM_YSH     (SM_A)                    // 32 x 64 bf16 = 4096
#define SM_GSH     (SM_YSH + 4096)           // 32 f32
#define SM_LTILE   (SM_GSH + 128)            // 4*32 f32
#define SMEM_BYTES (SM_LTILE + 512)

// ---- scope-templated global access (SC1=false: L2-local; true: device) ----
template<bool SC1>
__device__ __forceinline__ void st_b128_x(void* p, u32x4 v) {
    if constexpr (SC1)
        asm volatile("global_store_dwordx4 %0, %1, off sc0 sc1" :: "v"(p), "v"(v) : "memory");
    else
        asm volatile("global_store_dwordx4 %0, %1, off sc0" :: "v"(p), "v"(v) : "memory");
}
template<bool SC1>
__device__ __forceinline__ void st_b32_x(void* p, unsigned v) {
    if constexpr (SC1)
        asm volatile("global_store_dword %0, %1, off sc0 sc1" :: "v"(p), "v"(v) : "memory");
    else
        asm volatile("global_store_dword %0, %1, off sc0" :: "v"(p), "v"(v) : "memory");
}
template<bool SC1>
__device__ __forceinline__ void st_f32_x(void* p, float v) {
    if constexpr (SC1)
        asm volatile("global_store_dword %0, %1, off sc0 sc1" :: "v"(p), "v"(v) : "memory");
    else
        asm volatile("global_store_dword %0, %1, off sc0" :: "v"(p), "v"(v) : "memory");
}
template<bool SC1>
__device__ __forceinline__ u32x4 ld_b128_x(const void* p) {
    u32x4 r;
    if constexpr (SC1)
        asm volatile("global_load_dwordx4 %0, %1, off sc0 sc1" : "=v"(r) : "v"(p) : "memory");
    else
        asm volatile("global_load_dwordx4 %0, %1, off sc0" : "=v"(r) : "v"(p) : "memory");
    return r;
}
template<bool SC1>
__device__ __forceinline__ float ld_f32_x(const void* p) {
    float r;
    if constexpr (SC1)
        asm volatile("global_load_dword %0, %1, off sc0 sc1" : "=v"(r) : "v"(p) : "memory");
    else
        asm volatile("global_load_dword %0, %1, off sc0" : "=v"(r) : "v"(p) : "memory");
    return r;
}
template<bool SC1>
__device__ __forceinline__ unsigned ld_u32sync_x(const void* p) {
    unsigned r;
    if constexpr (SC1)
        asm volatile("global_load_dword %0, %1, off sc0 sc1\n\ts_waitcnt vmcnt(0)"
                     : "=v"(r) : "v"(p) : "memory");
    else
        asm volatile("global_load_dword %0, %1, off sc0\n\ts_waitcnt vmcnt(0)"
                     : "=v"(r) : "v"(p) : "memory");
    return r;
}
__device__ __forceinline__ void waitcnt_vm0() {
    asm volatile("s_waitcnt vmcnt(0)" ::: "memory");
    __builtin_amdgcn_sched_barrier(0);
}

__global__ void k_expA(const float* __restrict__ alpha, __bf16* __restrict__ Abf) {
    int idx = (blockIdx.x * 256 + threadIdx.x) * 4;
    float4 v = *(const float4*)(alpha + idx);
    union { __bf16 h[4]; uint2 u; } cv;
    cv.h[0] = (__bf16)__expf(v.x);
    cv.h[1] = (__bf16)__expf(v.y);
    cv.h[2] = (__bf16)__expf(v.z);
    cv.h[3] = (__bf16)__expf(v.w);
    *(uint2*)(Abf + idx) = cv.u;
}

// E[t][b][i] = beta[i, x[b,t]]
__global__ void k_gather(const int* __restrict__ x, const float* __restrict__ beta,
                         float* __restrict__ E) {
    int tb = blockIdx.x;            // t*32 + b
    int t  = tb >> 5, b = tb & 31;
    int xv = x[b * Tdim + t];
    int i  = threadIdx.x * 4;
    float4 v;
    v.x = beta[(size_t)(i + 0) * Vdim + xv];
    v.y = beta[(size_t)(i + 1) * Vdim + xv];
    v.z = beta[(size_t)(i + 2) * Vdim + xv];
    v.w = beta[(size_t)(i + 3) * Vdim + xv];
    *(float4*)(E + ((size_t)t * Bdim + b) * Hdim + i) = v;
}

template<bool SC1>
__device__ __forceinline__ void wait_flags(const char* lrec, int par, unsigned want) {
    if (threadIdx.x < 64) {
        const char* fp = lrec + ((size_t)par * NWG + (threadIdx.x & 15)) * 256 + 128;
        while (!__all((int)(ld_u32sync_x<SC1>(fp) >= want)))
            __builtin_amdgcn_s_sleep(1);
    }
    __syncthreads();
}

__device__ __forceinline__ void load_e(const float* __restrict__ E,
                                       const float* __restrict__ beta,
                                       const int* __restrict__ x,
                                       int t, int b0, int i0, int useE, float e[2][4]) {
    if (useE) {
        #pragma unroll
        for (int u = 0; u < 2; ++u)
            #pragma unroll
            for (int r = 0; r < 4; ++r)
                e[u][r] = E[((size_t)t * Bdim + (b0 + r)) * Hdim + i0 + u * 16];
    } else {
        int xv[4];
        #pragma unroll
        for (int r = 0; r < 4; ++r) xv[r] = x[(b0 + r) * Tdim + t];
        #pragma unroll
        for (int u = 0; u < 2; ++u)
            #pragma unroll
            for (int r = 0; r < 4; ++r)
                e[u][r] = beta[(size_t)(i0 + u * 16) * Vdim + xv[r]];
    }
}

// Publish: Y = exp(y - Gc) (LDS-staged, contiguous 4KB store), per-WG max, flag.
template<bool SC1>
__device__ __forceinline__ void store_phase(const float y[2][4], const float Gc[4],
                                            char* Yblk, char* Lrec_p,
                                            __bf16* Ysh, float* Ltile,
                                            int w, int li, int np, int b0,
                                            unsigned seq) {
    #pragma unroll
    for (int r = 0; r < 4; ++r) {
        #pragma unroll
        for (int u = 0; u < 2; ++u) {
            float Yn = __expf(y[u][r] - Gc[r]);
            Ysh[(b0 + r) * 64 + np * 32 + u * 16 + li] = (__bf16)Yn;
        }
        float m = fmaxf(y[0][r], y[1][r]);
        m = fmaxf(m, __shfl_xor(m, 1, 16));
        m = fmaxf(m, __shfl_xor(m, 2, 16));
        m = fmaxf(m, __shfl_xor(m, 4, 16));
        m = fmaxf(m, __shfl_xor(m, 8, 16));
        if (li == 0) Ltile[w * 32 + b0 + r] = m;
    }
    __syncthreads();
    const int tid = threadIdx.x;
    st_b128_x<SC1>(Yblk + tid * 16, ((const u32x4*)Ysh)[tid]);
    if (tid < 32) {
        int mbb = tid >> 4;
        float L = fmaxf(Ltile[mbb * 32 + tid], Ltile[(mbb + 2) * 32 + tid]);
        st_f32_x<SC1>(Lrec_p + tid * 4, L);
    }
    asm volatile("s_waitcnt vmcnt(0)" ::: "memory");
    __syncthreads();
    if (tid == 0) st_b32_x<SC1>(Lrec_p + 128, seq);
}

template<bool SC1>
__device__ __forceinline__ void hmm_body(const int* __restrict__ x,
                                         const float* __restrict__ beta,
                                         const float* __restrict__ gamma,
                                         char* __restrict__ Yb,
                                         char* __restrict__ lrec,
                                         float* __restrict__ Psum,
                                         float* __restrict__ Rbuf,
                                         const float* __restrict__ Ebuf, int useE,
                                         char* Asl, __bf16* Ysh, float* Gsh, float* Ltile,
                                         int p, int w, int li, int g, int mb, int np,
                                         int b0, int i0) {
    const int tid = threadIdx.x;

    // ---- init: y0 = e[:, T-1] ----
    {
        float y0[2][4];
        load_e(Ebuf, beta, x, Tdim - 1, b0, i0, useE, y0);
        float Gc0[4] = {0.f, 0.f, 0.f, 0.f};
        store_phase<SC1>(y0, Gc0, Yb + p * 4096, lrec + (size_t)p * 256,
                         Ysh, Ltile, w, li, np, b0, 1u);
    }

    float Nprev[4] = {0.f, 0.f, 0.f, 0.f};
    float ereg[2][4];
    load_e(Ebuf, beta, x, Tdim - 2, b0, i0, useE, ereg);

    for (int s = 1; s < Tdim; ++s) {
        const int t     = Tdim - 1 - s;
        const int par_r = (s - 1) & 1;
        const int par_w = s & 1;

        // prefetch next step's e (overlaps flag poll)
        float eregN[2][4];
        if (s < Tdim - 1) load_e(Ebuf, beta, x, t - 1, b0, i0, useE, eregN);

        float gl[2] = {0.f, 0.f};
        if (s == Tdim - 1) { gl[0] = gamma[i0]; gl[1] = gamma[i0 + 16]; }

        wait_flags<SC1>(lrec, par_r, (unsigned)s);

        // Y fragment loads: layout [blk=j>>6][b][j&63]
        const char* Ybase = Yb + (size_t)par_r * (NWG * 4096);
        const char* yrow  = Ybase + (mb * 16 + li) * 128 + g * 16;
        u32x4 yreg[32];
        #pragma unroll
        for (int kc = 0; kc < 32; ++kc)
            yreg[kc] = ld_b128_x<SC1>(yrow + (kc >> 1) * 4096 + (kc & 1) * 64);

        // per-WG maxes; reduce after the single vmcnt drain
        float gmv[16];
        const char* lbase = lrec + (size_t)par_r * NWG * 256;
        if (tid < 32) {
            #pragma unroll
            for (int q = 0; q < 16; ++q)
                gmv[q] = ld_f32_x<SC1>(lbase + q * 256 + tid * 4);
        }

        waitcnt_vm0();

        if (tid < 32) {
            float gm = gmv[0];
            #pragma unroll
            for (int q = 1; q < 16; ++q) gm = fmaxf(gm, gmv[q]);
            Gsh[tid] = gm;
        }
        __syncthreads();

        // ---- S[b, i-slice] = sum_j expA[i,j] * Y[b,j] ----
        f32x4 acc0 = {0.f, 0.f, 0.f, 0.f}, acc1 = {0.f, 0.f, 0.f, 0.f};
        {
            const int ia = np * 32 + li;
            const int ib = ia + 16;
            const int basea = ia * 2048 + g * 16, xa = (ia & 7) << 4;
            const int baseb = ib * 2048 + g * 16, xb = (ib & 7) << 4;
            #pragma unroll
            for (int kc = 0; kc < 32; ++kc) {
                bf16x8 af0 = *(const bf16x8*)(Asl + ((basea + kc * 64) ^ xa));
                bf16x8 af1 = *(const bf16x8*)(Asl + ((baseb + kc * 64) ^ xb));
                bf16x8 yf  = __builtin_bit_cast(bf16x8, yreg[kc]);
                acc0 = __builtin_amdgcn_mfma_f32_16x16x32_bf16(yf, af0, acc0, 0, 0, 0);
                acc1 = __builtin_amdgcn_mfma_f32_16x16x32_bf16(yf, af1, acc1, 0, 0, 0);
            }
        }

        float Gcur[4];
        #pragma unroll
        for (int r = 0; r < 4; ++r) Gcur[r] = Gsh[b0 + r];

        float yv[2][4];
        #pragma unroll
        for (int r = 0; r < 4; ++r) {
            yv[0][r] = Nprev[r] + __logf(acc0[r]) + ereg[0][r];
            yv[1][r] = Nprev[r] + __logf(acc1[r]) + ereg[1][r];
        }

        if (s < Tdim - 1) {
            store_phase<SC1>(yv, Gcur, Yb + (size_t)par_w * (NWG * 4096) + p * 4096,
                             lrec + ((size_t)par_w * NWG + p) * 256,
                             Ysh, Ltile, w, li, np, b0, (unsigned)(s + 1));
            #pragma unroll
            for (int r = 0; r < 4; ++r) Nprev[r] = Gcur[r];
            #pragma unroll
            for (int u = 0; u < 2; ++u)
                #pragma unroll
                for (int r = 0; r < 4; ++r) ereg[u][r] = eregN[u][r];
        } else {
            #pragma unroll
            for (int r = 0; r < 4; ++r) {
                float pa = __expf(gl[0] + yv[0][r] - Gcur[r])
                         + __expf(gl[1] + yv[1][r] - Gcur[r]);
                pa += __shfl_xor(pa, 1, 16);
                pa += __shfl_xor(pa, 2, 16);
                pa += __shfl_xor(pa, 4, 16);
                pa += __shfl_xor(pa, 8, 16);
                if (li == 0) {
                    atomicAdd(&Psum[b0 + r], pa);
                    if (p == 0) Rbuf[b0 + r] = Gcur[r];
                }
            }
        }
    }
}

__launch_bounds__(256, 1)
__global__ void k_hmm(const int* __restrict__ x,
                      const float* __restrict__ beta,
                      const float* __restrict__ gamma,
                      const __bf16* __restrict__ Abf,
                      char* __restrict__ Yb,
                      char* __restrict__ lrec,
                      float* __restrict__ Psum,
                      float* __restrict__ Rbuf,
                      int* __restrict__ ctl,        // [0]=homeXcd, [16]=slotCnt
                      char* __restrict__ ver,       // verTok @0 (16x4B), verOk @128
                      const float* __restrict__ Ebuf,
                      int useE)
{
    extern __shared__ char smem[];
    char*   Asl   = smem;
    __bf16* Ysh   = (__bf16*)(smem + SM_YSH);
    float*  Gsh   = (float*)(smem + SM_GSH);
    float*  Ltile = (float*)(smem + SM_LTILE);
    __shared__ int s_slot;
    __shared__ int s_fast;

    const int tid = threadIdx.x;

    // ---- claim a worker slot (home-XCD preferred; last 16 blocks claim
    //      unconditionally so slotCnt provably reaches NWG) ----
    if (tid == 0) {
        unsigned xcc;
        asm volatile("s_getreg_b32 %0, hwreg(HW_REG_XCC_ID)" : "=s"(xcc));
        int home = atomicCAS(ctl, -1, (int)xcc);
        if (home == -1) home = (int)xcc;
        int slot = -1;
        if ((int)xcc == home || blockIdx.x >= NBLK - NWG) {
            int sl = atomicAdd(ctl + 16, 1);
            if (sl < NWG) slot = sl;
        }
        s_slot = slot;
    }
    __syncthreads();
    const int p = s_slot;
    if (p < 0) return;

    const int w   = tid >> 6;
    const int l   = tid & 63;
    const int g   = l >> 4;
    const int li  = l & 15;
    const int mb  = w & 1;
    const int np  = w >> 1;
    const int b0  = mb * 16 + g * 4;
    const int i0  = p * SLICE + np * 32 + li;

    // ---- stage A slice into LDS (absorbs claim skew) ----
    #pragma unroll
    for (int rep = 0; rep < 32; ++rep) {
        int flat = rep * 256 + tid;
        int row  = flat >> 7;
        int c16  = flat & 127;
        uint4 v = *(const uint4*)((const char*)Abf + (size_t)(p * 64 + row) * 2048 + c16 * 16);
        int off = (row * 2048 + c16 * 16) ^ ((row & 7) << 4);
        *(uint4*)(Asl + off) = v;
    }
    __syncthreads();

    // ---- verification: can the 16 workers see each other's sc0 stores? ----
    if (tid < 64) {
        int ok = 1;
        #pragma unroll
        for (int round = 0; round < 2; ++round) {
            unsigned base = round ? 0xA5000000u : 0x5A000000u;
            if (tid == 0) {
                st_b32_x<false>(ver + p * 4, base | (unsigned)p);
                asm volatile("s_waitcnt vmcnt(0)" ::: "memory");
            }
            int seen = 1;
            if (tid < 16) {
                const char* tp = ver + tid * 4;
                unsigned expect = base | (unsigned)tid;
                seen = 0;
                for (int it = 0; it < VBOUND; ++it) {
                    if (ld_u32sync_x<false>(tp) == expect) { seen = 1; break; }
                    __builtin_amdgcn_s_sleep(1);
                }
            }
            ok &= __all(seen);
        }
        // publish verdict through the reliable (sc1) channel; gather all 16
        if (tid == 0) {
            st_b32_x<true>(ver + 128 + p * 4, ok ? 1u : 2u);
            asm volatile("s_waitcnt vmcnt(0)" ::: "memory");
        }
        int myfast = 1;
        if (tid < 16) {
            const char* vp = ver + 128 + tid * 4;
            unsigned v;
            while ((v = ld_u32sync_x<true>(vp)) == 0u)
                __builtin_amdgcn_s_sleep(1);
            myfast = (v == 1u);
        }
        int f = __all(myfast);
        if (tid == 0) s_fast = f;
    }
    __syncthreads();
    const int fast = s_fast;

    if (fast)
        hmm_body<false>(x, beta, gamma, Yb, lrec, Psum, Rbuf, Ebuf, useE,
                        Asl, Ysh, Gsh, Ltile, p, w, li, g, mb, np, b0, i0);
    else
        hmm_body<true>(x, beta, gamma, Yb, lrec, Psum, Rbuf, Ebuf, useE,
                       Asl, Ysh, Gsh, Ltile, p, w, li, g, mb, np, b0, i0);
}

__global__ void k_final(const float* __restrict__ Psum, const float* __restrict__ Rbuf,
                        float* __restrict__ out) {
    int b = threadIdx.x;
    if (b < 32) out[b] = Rbuf[b] + __logf(Psum[b]);
}

extern "C" void kernel_launch(void* const* d_in, const int* in_sizes, int n_in,
                              void* d_out, int out_size, void* d_ws, size_t ws_size,
                              hipStream_t stream) {
    const int*   x     = (const int*)d_in[0];
    const float* alpha = (const float*)d_in[1];
    const float* beta  = (const float*)d_in[2];
    const float* gamma = (const float*)d_in[3];

    char* ws = (char*)d_ws;
    __bf16* Abf  = (__bf16*)(ws + OFF_ABF);
    char*   Yb   = ws + OFF_YBUF;
    float*  Psum = (float*)(ws + OFF_PSUM);
    float*  Rbuf = (float*)(ws + OFF_RBUF);
    char*   lrec = ws + OFF_LREC;
    int*    ctl  = (int*)(ws + OFF_CTL);
    char*   ver  = ws + OFF_VER;
    float*  Ebuf = (float*)(ws + OFF_E);

    int useE = (ws_size >= WS_E_NEED) ? 1 : 0;

    // zero Psum/Rbuf/records/ctl/ver each launch, then set homeXcd = -1
    (void)hipMemsetAsync(ws + OFF_PSUM, 0, OFF_END0 - OFF_PSUM, stream);
    (void)hipMemsetAsync(ws + OFF_CTL, 0xFF, 4, stream);

    hipLaunchKernelGGL(k_expA, dim3((Hdim * Hdim) / (256 * 4)), dim3(256), 0, stream, alpha, Abf);

    if (useE)
        hipLaunchKernelGGL(k_gather, dim3(Tdim * Bdim), dim3(256), 0, stream, x, beta, Ebuf);

    (void)hipFuncSetAttribute((const void*)k_hmm, hipFuncAttributeMaxDynamicSharedMemorySize, SMEM_BYTES);
    hipLaunchKernelGGL(k_hmm, dim3(NBLK), dim3(256), SMEM_BYTES, stream,
                       x, beta, gamma, Abf, Yb, lrec, Psum, Rbuf, ctl, ver,
                       useE ? Ebuf : (const float*)nullptr, useE);

    hipLaunchKernelGGL(k_final, dim3(1), dim3(64), 0, stream, Psum, Rbuf, (float*)d_out);
}

// Round 7
// 2017.679 us; speedup vs baseline: 1.7926x; 1.7926x over previous
//
#include <hip/hip_runtime.h>
#include <hip/hip_bf16.h>

// HMM backward recursion, B=32, T=256, H=1024, V=50257.
// y_s[b,i] = N_{s-1}[b] + log( sum_j expA[i,j] * Y_{s-1}[b,j] ) + e_t[b,i]
// Y_s = exp(y_s - N_s), N_s = max_i y_{s-1}[b,i] (one-step-stale upper bound).
// 16 persistent WGs, exchange via sc0sc1 (device-scope, L3) loads/stores.
// Fully barrier-free step loop: per-WAVE publish (direct reg stores + own
// vmcnt drain + own flag; 64 flags) and per-wave consume (poll + register
// max-reduce + __shfl broadcast). No __syncthreads after init.

#define Hdim 1024
#define Bdim 32
#define Tdim 256
#define Vdim 50257
#define NWG  16
#define SLICE 64

typedef __attribute__((ext_vector_type(8))) __bf16 bf16x8;
typedef __attribute__((ext_vector_type(4))) float  f32x4;
typedef __attribute__((ext_vector_type(4))) unsigned u32x4;

// workspace layout (bytes)
#define OFF_ABF   0                          // exp(alpha) bf16: 2 MB
#define OFF_YBUF  2097152                    // [2][16][4096B] = 131072
#define OFF_PSUM  (OFF_YBUF + 131072)        // 32 f32 (pad 128)
#define OFF_RBUF  (OFF_PSUM + 128)           // 32 f32 (pad 128)
#define OFF_WREC  (OFF_RBUF + 128)           // [2][16][4] x 64B = 8192
#define OFF_FLG   (OFF_WREC + 8192)          // [2][64] x 64B = 8192
#define OFF_END0  (OFF_FLG + 8192)
#define OFF_E     (((OFF_END0) + 4095) & ~4095)
#define WS_E_NEED ((size_t)OFF_E + (size_t)Tdim * Bdim * Hdim * 4)

// LDS carve
#define SM_A       131072                    // 64 rows x 1024 bf16 (swizzled)
#define SMEM_BYTES (SM_A + 256)

// ---- sc0 sc1 (device-scope, cache-bypass to L3) access helpers ----
__device__ __forceinline__ void st_b128_sc(void* p, u32x4 v) {
    asm volatile("global_store_dwordx4 %0, %1, off sc0 sc1" :: "v"(p), "v"(v) : "memory");
}
__device__ __forceinline__ void st_b32_sc(void* p, unsigned v) {
    asm volatile("global_store_dword %0, %1, off sc0 sc1" :: "v"(p), "v"(v) : "memory");
}
__device__ __forceinline__ void st_b16_sc(void* p, unsigned v) {
    asm volatile("global_store_short %0, %1, off sc0 sc1" :: "v"(p), "v"(v) : "memory");
}
__device__ __forceinline__ u32x4 ld_b128_sc(const void* p) {
    u32x4 r;
    asm volatile("global_load_dwordx4 %0, %1, off sc0 sc1" : "=v"(r) : "v"(p) : "memory");
    return r;
}
__device__ __forceinline__ float ld_f32_sc(const void* p) {
    float r;
    asm volatile("global_load_dword %0, %1, off sc0 sc1" : "=v"(r) : "v"(p) : "memory");
    return r;
}
__device__ __forceinline__ unsigned ld_u32sync_sc(const void* p) {
    unsigned r;
    asm volatile("global_load_dword %0, %1, off sc0 sc1\n\ts_waitcnt vmcnt(0)"
                 : "=v"(r) : "v"(p) : "memory");
    return r;
}
__device__ __forceinline__ void waitcnt_vm0() {
    asm volatile("s_waitcnt vmcnt(0)" ::: "memory");
    __builtin_amdgcn_sched_barrier(0);
}
__device__ __forceinline__ void waitcnt_vm32() {
    asm volatile("s_waitcnt vmcnt(32)" ::: "memory");
    __builtin_amdgcn_sched_barrier(0);
}

__global__ void k_expA(const float* __restrict__ alpha, __bf16* __restrict__ Abf) {
    int idx = (blockIdx.x * 256 + threadIdx.x) * 4;
    float4 v = *(const float4*)(alpha + idx);
    union { __bf16 h[4]; uint2 u; } cv;
    cv.h[0] = (__bf16)__expf(v.x);
    cv.h[1] = (__bf16)__expf(v.y);
    cv.h[2] = (__bf16)__expf(v.z);
    cv.h[3] = (__bf16)__expf(v.w);
    *(uint2*)(Abf + idx) = cv.u;
}

// E[t][b][i] = beta[i, x[b,t]]
__global__ void k_gather(const int* __restrict__ x, const float* __restrict__ beta,
                         float* __restrict__ E) {
    int tb = blockIdx.x;            // t*32 + b
    int t  = tb >> 5, b = tb & 31;
    int xv = x[b * Tdim + t];
    int i  = threadIdx.x * 4;
    float4 v;
    v.x = beta[(size_t)(i + 0) * Vdim + xv];
    v.y = beta[(size_t)(i + 1) * Vdim + xv];
    v.z = beta[(size_t)(i + 2) * Vdim + xv];
    v.w = beta[(size_t)(i + 3) * Vdim + xv];
    *(float4*)(E + ((size_t)t * Bdim + b) * Hdim + i) = v;
}

__device__ __forceinline__ void load_e(const float* __restrict__ E,
                                       const float* __restrict__ beta,
                                       const int* __restrict__ x,
                                       int t, int b0, int i0, int useE, float e[2][4]) {
    if (useE) {
        #pragma unroll
        for (int u = 0; u < 2; ++u)
            #pragma unroll
            for (int r = 0; r < 4; ++r)
                e[u][r] = E[((size_t)t * Bdim + (b0 + r)) * Hdim + i0 + u * 16];
    } else {
        int xv[4];
        #pragma unroll
        for (int r = 0; r < 4; ++r) xv[r] = x[(b0 + r) * Tdim + t];
        #pragma unroll
        for (int u = 0; u < 2; ++u)
            #pragma unroll
            for (int r = 0; r < 4; ++r)
                e[u][r] = beta[(size_t)(i0 + u * 16) * Vdim + xv[r]];
    }
}

// Per-WAVE publish: Y sub-tile direct from regs (8x b16 stores), 16 per-b
// maxes as one dwordx4 (leader lanes), own vmcnt drain, own flag. No barrier.
__device__ __forceinline__ void publish_wave(const float y[2][4], const float Gc[4],
                                             char* Yblk,     // Ybuf[par] + p*4096
                                             char* wrec_pw,  // wrec[par][p][w]
                                             char* flg_pw,   // flg[par][p*4+w]
                                             int li, int g, int np, int b0,
                                             unsigned seq) {
    float mx[4];
    #pragma unroll
    for (int r = 0; r < 4; ++r) {
        #pragma unroll
        for (int u = 0; u < 2; ++u) {
            float Yn = __expf(y[u][r] - Gc[r]);
            __bf16 h = (__bf16)Yn;
            unsigned hv = (unsigned)__builtin_bit_cast(unsigned short, h);
            st_b16_sc(Yblk + (b0 + r) * 128 + (np * 32 + u * 16 + li) * 2, hv);
        }
        float m = fmaxf(y[0][r], y[1][r]);
        m = fmaxf(m, __shfl_xor(m, 1, 16));
        m = fmaxf(m, __shfl_xor(m, 2, 16));
        m = fmaxf(m, __shfl_xor(m, 4, 16));
        m = fmaxf(m, __shfl_xor(m, 8, 16));
        mx[r] = m;
    }
    if (li == 0) {
        f32x4 mv = {mx[0], mx[1], mx[2], mx[3]};
        st_b128_sc(wrec_pw + g * 16, __builtin_bit_cast(u32x4, mv));
    }
    asm volatile("s_waitcnt vmcnt(0)" ::: "memory");
    if ((threadIdx.x & 63) == 0) st_b32_sc(flg_pw, seq);
}

__launch_bounds__(256, 1)
__global__ void k_hmm(const int* __restrict__ x,
                      const float* __restrict__ beta,
                      const float* __restrict__ gamma,
                      const __bf16* __restrict__ Abf,
                      char* __restrict__ Yb,        // [2][16][4096B]
                      char* __restrict__ wrec,      // [2][16][4] x 64B
                      char* __restrict__ flg,       // [2][64] x 64B
                      float* __restrict__ Psum,
                      float* __restrict__ Rbuf,
                      const float* __restrict__ Ebuf,
                      int useE)
{
    extern __shared__ char smem[];
    char* Asl = smem;

    const int p   = blockIdx.x;
    const int tid = threadIdx.x;
    const int w   = tid >> 6;
    const int l   = tid & 63;
    const int g   = l >> 4;
    const int li  = l & 15;
    const int mb  = w & 1;
    const int np  = w >> 1;
    const int b0  = mb * 16 + g * 4;
    const int i0  = p * SLICE + np * 32 + li;

    // ---- stage A slice into LDS, XOR-swizzled for b128 reads ----
    #pragma unroll
    for (int rep = 0; rep < 32; ++rep) {
        int flat = rep * 256 + tid;
        int row  = flat >> 7;
        int c16  = flat & 127;
        uint4 v = *(const uint4*)((const char*)Abf + (size_t)(p * 64 + row) * 2048 + c16 * 16);
        int off = (row * 2048 + c16 * 16) ^ ((row & 7) << 4);
        *(uint4*)(Asl + off) = v;
    }
    __syncthreads();    // only barrier in the kernel (A staging)

    // ---- init: y0 = e[:, T-1], publish per-wave ----
    {
        float y0[2][4];
        load_e(Ebuf, beta, x, Tdim - 1, b0, i0, useE, y0);
        float Gc0[4] = {0.f, 0.f, 0.f, 0.f};
        publish_wave(y0, Gc0, Yb + p * 4096,
                     wrec + (size_t)p * 256 + w * 64,
                     flg + (size_t)(p * 4 + w) * 64,
                     li, g, np, b0, 1u);
    }

    float Nprev[4] = {0.f, 0.f, 0.f, 0.f};
    float ereg[2][4];
    load_e(Ebuf, beta, x, Tdim - 2, b0, i0, useE, ereg);

    for (int s = 1; s < Tdim; ++s) {
        const int t     = Tdim - 1 - s;
        const int par_r = (s - 1) & 1;
        const int par_w = s & 1;

        // prefetch next step's e; drain BEFORE polling so the detect loop
        // never waits on an E (possibly HBM) load
        float eregN[2][4];
        if (s < Tdim - 1) load_e(Ebuf, beta, x, t - 1, b0, i0, useE, eregN);
        float gl[2] = {0.f, 0.f};
        if (s == Tdim - 1) { gl[0] = gamma[i0]; gl[1] = gamma[i0 + 16]; }
        waitcnt_vm0();

        // ---- poll all 64 producer-wave flags (each wave independently) ----
        {
            const char* fp = flg + (size_t)par_r * 4096 + l * 64;
            while (!__all((int)(ld_u32sync_sc(fp) >= (unsigned)s))) {}
        }

        // ---- issue Y loads (32 b128), then wrec loads (32 f32, lanes<32) ----
        const char* Ybase = Yb + (size_t)par_r * (NWG * 4096);
        const char* yrow  = Ybase + (mb * 16 + li) * 128 + g * 16;
        u32x4 yreg[32];
        #pragma unroll
        for (int kc = 0; kc < 32; ++kc)
            yreg[kc] = ld_b128_sc(yrow + (kc >> 1) * 4096 + (kc & 1) * 64);

        float gmv[32];
        {
            const char* wbase = wrec + (size_t)par_r * 4096;
            if (l < 32) {
                int bmb = l >> 4;          // 16-block of b
                int idx = (l & 15) * 4;
                #pragma unroll
                for (int q = 0; q < 16; ++q) {
                    gmv[2 * q]     = ld_f32_sc(wbase + q * 256 + bmb * 64 + idx);
                    gmv[2 * q + 1] = ld_f32_sc(wbase + q * 256 + (bmb + 2) * 64 + idx);
                }
            }
        }

        waitcnt_vm32();   // Y loads (oldest 32) done; wrec still in flight

        // ---- S[b, i-slice] = sum_j expA[i,j] * Y[b,j] ----
        f32x4 acc0 = {0.f, 0.f, 0.f, 0.f}, acc1 = {0.f, 0.f, 0.f, 0.f};
        {
            const int ia = np * 32 + li;
            const int ib = ia + 16;
            const int basea = ia * 2048 + g * 16, xa = (ia & 7) << 4;
            const int baseb = ib * 2048 + g * 16, xb = (ib & 7) << 4;
            #pragma unroll
            for (int kc = 0; kc < 32; ++kc) {
                bf16x8 af0 = *(const bf16x8*)(Asl + ((basea + kc * 64) ^ xa));
                bf16x8 af1 = *(const bf16x8*)(Asl + ((baseb + kc * 64) ^ xb));
                bf16x8 yf  = __builtin_bit_cast(bf16x8, yreg[kc]);
                acc0 = __builtin_amdgcn_mfma_f32_16x16x32_bf16(yf, af0, acc0, 0, 0, 0);
                acc1 = __builtin_amdgcn_mfma_f32_16x16x32_bf16(yf, af1, acc1, 0, 0, 0);
            }
        }

        waitcnt_vm0();    // wrec loads done

        // per-b global max in registers + wave-local broadcast (no LDS)
        float gm = -3.0e38f;
        if (l < 32) {
            #pragma unroll
            for (int q = 0; q < 32; ++q) gm = fmaxf(gm, gmv[q]);
        }
        float Gcur[4];
        #pragma unroll
        for (int r = 0; r < 4; ++r) Gcur[r] = __shfl(gm, b0 + r);

        float yv[2][4];
        #pragma unroll
        for (int r = 0; r < 4; ++r) {
            yv[0][r] = Nprev[r] + __logf(acc0[r]) + ereg[0][r];
            yv[1][r] = Nprev[r] + __logf(acc1[r]) + ereg[1][r];
        }

        if (s < Tdim - 1) {
            publish_wave(yv, Gcur,
                         Yb + (size_t)par_w * (NWG * 4096) + p * 4096,
                         wrec + (size_t)par_w * 4096 + (size_t)p * 256 + w * 64,
                         flg + (size_t)par_w * 4096 + (size_t)(p * 4 + w) * 64,
                         li, g, np, b0, (unsigned)(s + 1));
            #pragma unroll
            for (int r = 0; r < 4; ++r) Nprev[r] = Gcur[r];
            #pragma unroll
            for (int u = 0; u < 2; ++u)
                #pragma unroll
                for (int r = 0; r < 4; ++r) ereg[u][r] = eregN[u][r];
        } else {
            #pragma unroll
            for (int r = 0; r < 4; ++r) {
                float pa = __expf(gl[0] + yv[0][r] - Gcur[r])
                         + __expf(gl[1] + yv[1][r] - Gcur[r]);
                pa += __shfl_xor(pa, 1, 16);
                pa += __shfl_xor(pa, 2, 16);
                pa += __shfl_xor(pa, 4, 16);
                pa += __shfl_xor(pa, 8, 16);
                if (li == 0) {
                    atomicAdd(&Psum[b0 + r], pa);
                    if (p == 0) Rbuf[b0 + r] = Gcur[r];
                }
            }
        }
    }
}

__global__ void k_final(const float* __restrict__ Psum, const float* __restrict__ Rbuf,
                        float* __restrict__ out) {
    int b = threadIdx.x;
    if (b < 32) out[b] = Rbuf[b] + __logf(Psum[b]);
}

extern "C" void kernel_launch(void* const* d_in, const int* in_sizes, int n_in,
                              void* d_out, int out_size, void* d_ws, size_t ws_size,
                              hipStream_t stream) {
    const int*   x     = (const int*)d_in[0];
    const float* alpha = (const float*)d_in[1];
    const float* beta  = (const float*)d_in[2];
    const float* gamma = (const float*)d_in[3];

    char* ws = (char*)d_ws;
    __bf16* Abf  = (__bf16*)(ws + OFF_ABF);
    char*   Yb   = ws + OFF_YBUF;
    float*  Psum = (float*)(ws + OFF_PSUM);
    float*  Rbuf = (float*)(ws + OFF_RBUF);
    char*   wrec = ws + OFF_WREC;
    char*   flg  = ws + OFF_FLG;
    float*  Ebuf = (float*)(ws + OFF_E);

    int useE = (ws_size >= WS_E_NEED) ? 1 : 0;

    // zero Psum/Rbuf/wrec/flags every launch
    (void)hipMemsetAsync(ws + OFF_PSUM, 0, OFF_END0 - OFF_PSUM, stream);

    hipLaunchKernelGGL(k_expA, dim3((Hdim * Hdim) / (256 * 4)), dim3(256), 0, stream, alpha, Abf);

    if (useE)
        hipLaunchKernelGGL(k_gather, dim3(Tdim * Bdim), dim3(256), 0, stream, x, beta, Ebuf);

    (void)hipFuncSetAttribute((const void*)k_hmm, hipFuncAttributeMaxDynamicSharedMemorySize, SMEM_BYTES);
    hipLaunchKernelGGL(k_hmm, dim3(NWG), dim3(256), SMEM_BYTES, stream,
                       x, beta, gamma, Abf, Yb, wrec, flg, Psum, Rbuf,
                       useE ? Ebuf : (const float*)nullptr, useE);

    hipLaunchKernelGGL(k_final, dim3(1), dim3(64), 0, stream, Psum, Rbuf, (float*)d_out);
}